// Round 5
// baseline (506.510 us; speedup 1.0000x reference)
//
#include <hip/hip_runtime.h>
#include <math.h>

#define NTHREADS 256
#define EPSC 1e-6f
#define NPL 3   // node slots per lane in pos_fused: covers up to 192 nodes/graph

#define MB 32    // rows per block in mega_h (100000 = 3125 * 32, exact)
#define PZ 264   // zh/T1 LDS pitch in ushorts (row step = 4 banks -> 2-way, free)
#define PB 40    // staging LDS pitch in ushorts (row step = 20 banks -> 2-way, free)

typedef short bf16x8 __attribute__((ext_vector_type(8)));
typedef float f32x4  __attribute__((ext_vector_type(4)));

// ---------------------------------------------------------------------------
// helpers
// ---------------------------------------------------------------------------
__device__ __forceinline__ ushort f2bf(float x) {   // RNE float->bf16
  union { float f; unsigned u; } v; v.f = x;
  unsigned r = v.u + 0x7FFFu + ((v.u >> 16) & 1u);
  return (ushort)(r >> 16);
}
__device__ __forceinline__ float tanh_fast(float x) {
  float xc = fminf(fmaxf(x, -15.f), 15.f);
  float e = __expf(2.f * xc);
  return (e - 1.f) / (e + 1.f);
}

__device__ __forceinline__ void inv3x3(const float m[9], float o[9]) {
  float a=m[0],b=m[1],c=m[2],d=m[3],e=m[4],f=m[5],g=m[6],h=m[7],i=m[8];
  float det = a*e*i + b*f*g + d*h*c - g*e*c - a*h*f - d*b*i;
  float r = 1.0f/det;
  o[0]=(e*i-f*h)*r; o[1]=(c*h-b*i)*r; o[2]=(b*f-c*e)*r;
  o[3]=(f*g-d*i)*r; o[4]=(a*i-c*g)*r; o[5]=(c*d-a*f)*r;
  o[6]=(d*h-e*g)*r; o[7]=(b*g-a*h)*r; o[8]=(a*e-b*d)*r;
}

__device__ __forceinline__ float wred(float v) {
#pragma unroll
  for (int o = 32; o > 0; o >>= 1) v += __shfl_xor(v, o, 64);
  return v;
}

__device__ __forceinline__ void block_reduce_atomic(double v, double* target) {
#pragma unroll
  for (int off = 32; off > 0; off >>= 1) v += __shfl_down(v, off, 64);
  __shared__ double sm[NTHREADS/64];
  int lane = threadIdx.x & 63, wv = threadIdx.x >> 6;
  if (lane == 0) sm[wv] = v;
  __syncthreads();
  if (threadIdx.x == 0) {
    double s = 0.0;
#pragma unroll
    for (int i = 0; i < NTHREADS/64; ++i) s += sm[i];
    atomicAdd(target, s);
  }
}

// ---------------------------------------------------------------------------
// Fused pos branch: one wave per graph (unchanged; verified absmax 0.0)
// ---------------------------------------------------------------------------
__global__ __launch_bounds__(64) void pos_fused(
    int N, const float* __restrict__ pos, const float* __restrict__ epsp,
    const int* __restrict__ index, const float* __restrict__ t,
    const float* __restrict__ gpp, double* __restrict__ lossp)
{
  const int b = blockIdx.x;
  const int lane = threadIdx.x;

  int lo = 0, hi = N;
  while (lo < hi) { int mid = (lo + hi) >> 1; if (index[mid] < b) lo = mid + 1; else hi = mid; }
  const int start = lo;
  hi = N;
  while (lo < hi) { int mid = (lo + hi) >> 1; if (index[mid] < b + 1) lo = mid + 1; else hi = mid; }
  const int end = lo;
  const int cnt = end - start;
  const float fn = (float)cnt, rc = 1.0f / fn;

  const float tn  = t[b];
  const float a1  = 0.2f + 0.8f*tn, b1 = 0.1f*tn;
  const float omt = 1.0f - tn;
  const float sp  = log1pf(expf(gpp[0]));
  const float gp  = 0.1f + sp*tn;
  const float hg  = 0.5f*gp*gp;
  const float rgp = 1.0f/gp;
  const float pscale = 1.0f - 0.9f*omt;

  float iU[NPL][9], yv[NPL][3], wv[NPL][3], dwv[NPL][3], pv[NPL][3];
  float Vs[9] = {0}, wb[3] = {0}, dwb[3] = {0}, yb[3] = {0};
#pragma unroll
  for (int k = 0; k < NPL; ++k) {
    const int n = start + k*64 + lane;
    if (n < end) {
      const float px = pos[3*(size_t)n+0], py = pos[3*(size_t)n+1], pz = pos[3*(size_t)n+2];
      const float ex = epsp[3*(size_t)n+0], ey = epsp[3*(size_t)n+1], ez = epsp[3*(size_t)n+2];
      pv[k][0]=px; pv[k][1]=py; pv[k][2]=pz;
      const float pn = sqrtf(px*px+py*py+pz*pz) + EPSC;
      const float nx = px/pn, ny = py/pn, nz = pz/pn;
      const float nd = nx*ex + ny*ey + nz*ez;
      wv[k][0]=a1*ex + b1*nd*nx; wv[k][1]=a1*ey + b1*nd*ny; wv[k][2]=a1*ez + b1*nd*nz;
      dwv[k][0]=0.8f*ex + 0.1f*nd*nx; dwv[k][1]=0.8f*ey + 0.1f*nd*ny; dwv[k][2]=0.8f*ez + 0.1f*nd*nz;
      const float U[9] = { a1 + b1*nx*nx, b1*nx*ny,      b1*nx*nz,
                           b1*ny*nx,      a1 + b1*ny*ny, b1*ny*nz,
                           b1*nz*nx,      b1*nz*ny,      a1 + b1*nz*nz };
      inv3x3(U, iU[k]);
      yv[k][0] = iU[k][0]*ex + iU[k][3]*ey + iU[k][6]*ez;
      yv[k][1] = iU[k][1]*ex + iU[k][4]*ey + iU[k][7]*ez;
      yv[k][2] = iU[k][2]*ex + iU[k][5]*ey + iU[k][8]*ez;
#pragma unroll
      for (int j = 0; j < 9; ++j) Vs[j] += iU[k][j];
#pragma unroll
      for (int j = 0; j < 3; ++j) { wb[j]+=wv[k][j]; dwb[j]+=dwv[k][j]; yb[j]+=yv[k][j]; }
    }
  }
#pragma unroll
  for (int j = 0; j < 9; ++j) Vs[j] = wred(Vs[j]);
#pragma unroll
  for (int j = 0; j < 3; ++j) { wb[j]=wred(wb[j]); dwb[j]=wred(dwb[j]); yb[j]=wred(yb[j]); }

  float iV[9]; inv3x3(Vs, iV);
  float wm[3], dwm[3], u1[3], s1m[3];
#pragma unroll
  for (int i = 0; i < 3; ++i) { wm[i] = wb[i]*rc; dwm[i] = dwb[i]*rc; }
#pragma unroll
  for (int i = 0; i < 3; ++i) u1[i] = iV[0*3+i]*yb[0] + iV[1*3+i]*yb[1] + iV[2*3+i]*yb[2];
#pragma unroll
  for (int i = 0; i < 3; ++i) {
    const float csy = Vs[0*3+i]*u1[0] + Vs[1*3+i]*u1[1] + Vs[2*3+i]*u1[2] - fn*u1[i];
    s1m[i] = (csy - yb[i]) * rc;
  }

  float tg[NPL][3], zp[NPL][3], iU2[NPL][9], qv[NPL][3];
  float Vs2[9] = {0}, qs[3] = {0}, ps[3] = {0};
#pragma unroll
  for (int k = 0; k < NPL; ++k) {
    const int n = start + k*64 + lane;
    if (n < end) {
#pragma unroll
      for (int i = 0; i < 3; ++i) {
        const float c1 = iU[k][0*3+i]*u1[0] + iU[k][1*3+i]*u1[1] + iU[k][2*3+i]*u1[2] - u1[i];
        const float score1 = c1 - yv[k][i] - s1m[i];
        tg[k][i] = -pv[k][i] + dwv[k][i] - dwm[i] - hg*score1;
        zp[k][i] = pv[k][i]*omt + wv[k][i] - wm[i];
      }
      const float rx = 0.9f*zp[k][0], ry = 0.9f*zp[k][1], rz = 0.9f*zp[k][2];
      const float rn = sqrtf(rx*rx+ry*ry+rz*rz) + EPSC;
      const float nx = rx/rn, ny = ry/rn, nz = rz/rn;
      const float U2[9] = { a1 + b1*nx*nx, b1*nx*ny,      b1*nx*nz,
                            b1*ny*nx,      a1 + b1*ny*ny, b1*ny*nz,
                            b1*nz*nx,      b1*nz*ny,      a1 + b1*nz*nz };
      inv3x3(U2, iU2[k]);
      float prel[3];
#pragma unroll
      for (int i = 0; i < 3; ++i) prel[i] = zp[k][i]*pscale;
#pragma unroll
      for (int i = 0; i < 3; ++i)
        qv[k][i] = iU2[k][i*3+0]*prel[0] + iU2[k][i*3+1]*prel[1] + iU2[k][i*3+2]*prel[2];
#pragma unroll
      for (int j = 0; j < 9; ++j) Vs2[j] += iU2[k][j];
#pragma unroll
      for (int j = 0; j < 3; ++j) { qs[j] += qv[k][j]; ps[j] += prel[j]; }
    }
  }
#pragma unroll
  for (int j = 0; j < 9; ++j) Vs2[j] = wred(Vs2[j]);
#pragma unroll
  for (int j = 0; j < 3; ++j) { qs[j] = wred(qs[j]); ps[j] = wred(ps[j]); }

  float iV2[9]; inv3x3(Vs2, iV2);
  float cb2[3];
#pragma unroll
  for (int i = 0; i < 3; ++i)
    cb2[i] = iV2[i*3+0]*(qs[0]-ps[0]) + iV2[i*3+1]*(qs[1]-ps[1]) + iV2[i*3+2]*(qs[2]-ps[2]);

  float y2v[NPL][3], dw2v[NPL][3];
  float yb2[3] = {0}, dwb2[3] = {0};
#pragma unroll
  for (int k = 0; k < NPL; ++k) {
    const int n = start + k*64 + lane;
    if (n < end) {
      float e[3];
#pragma unroll
      for (int i = 0; i < 3; ++i)
        e[i] = qv[k][i] - (iU2[k][i*3+0]*cb2[0] + iU2[k][i*3+1]*cb2[1] + iU2[k][i*3+2]*cb2[2]);
#pragma unroll
      for (int i = 0; i < 3; ++i)
        y2v[k][i] = iU2[k][0*3+i]*e[0] + iU2[k][1*3+i]*e[1] + iU2[k][2*3+i]*e[2];
      const float rx = 0.9f*zp[k][0], ry = 0.9f*zp[k][1], rz = 0.9f*zp[k][2];
      const float rn = sqrtf(rx*rx+ry*ry+rz*rz) + EPSC;
      const float nx = rx/rn, ny = ry/rn, nz = rz/rn;
      const float nd = nx*e[0] + ny*e[1] + nz*e[2];
      dw2v[k][0] = 0.8f*e[0] + 0.1f*nd*nx;
      dw2v[k][1] = 0.8f*e[1] + 0.1f*nd*ny;
      dw2v[k][2] = 0.8f*e[2] + 0.1f*nd*nz;
#pragma unroll
      for (int j = 0; j < 3; ++j) { yb2[j] += y2v[k][j]; dwb2[j] += dw2v[k][j]; }
    }
  }
#pragma unroll
  for (int j = 0; j < 3; ++j) { yb2[j] = wred(yb2[j]); dwb2[j] = wred(dwb2[j]); }

  float u2[3], s2m[3], dw2m[3];
#pragma unroll
  for (int i = 0; i < 3; ++i) u2[i] = iV2[0*3+i]*yb2[0] + iV2[1*3+i]*yb2[1] + iV2[2*3+i]*yb2[2];
#pragma unroll
  for (int i = 0; i < 3; ++i) {
    const float csy = Vs2[0*3+i]*u2[0] + Vs2[1*3+i]*u2[1] + Vs2[2*3+i]*u2[2] - fn*u2[i];
    s2m[i] = (csy - yb2[i]) * rc;
    dw2m[i] = dwb2[i] * rc;
  }

  float acc = 0.0f;
#pragma unroll
  for (int k = 0; k < NPL; ++k) {
    const int n = start + k*64 + lane;
    if (n < end) {
#pragma unroll
      for (int i = 0; i < 3; ++i) {
        const float c2 = iU2[k][0*3+i]*u2[0] + iU2[k][1*3+i]*u2[1] + iU2[k][2*3+i]*u2[2] - u2[i];
        const float score2 = c2 - y2v[k][i] - s2m[i];
        const float dz2 = -0.9f*zp[k][i] + dw2v[k][i] - dw2m[i];
        const float apx = dz2 - hg*score2;
        const float d = (apx - tg[k][i]) * rgp;
        acc += d*d;
      }
    }
  }
  acc = wred(acc);
  if (lane == 0) atomicAdd(lossp, (double)acc);
}

// ---------------------------------------------------------------------------
// weight-prep kernels (tiny, run once per launch)
// ---------------------------------------------------------------------------
__global__ __launch_bounds__(NTHREADS) void cvt_bf16(
    const float4* __restrict__ in, ushort4* __restrict__ out, int n4)
{
  for (int i = blockIdx.x*blockDim.x + threadIdx.x; i < n4; i += gridDim.x*blockDim.x) {
    float4 v = in[i];
    out[i] = make_ushort4(f2bf(v.x), f2bf(v.y), f2bf(v.z), f2bf(v.w));
  }
}

// out[n][k] = bf16(in[k][n]);  K, Nn multiples of 32
__global__ __launch_bounds__(NTHREADS) void transpose_cvt(
    const float* __restrict__ in, ushort* __restrict__ out, int K, int Nn)
{
  __shared__ float ts[32][33];
  const int tx = threadIdx.x & 31, ty = threadIdx.x >> 5;   // 32 x 8
  const int nb = blockIdx.x*32, kb = blockIdx.y*32;
#pragma unroll
  for (int r = 0; r < 4; ++r)
    ts[ty + r*8][tx] = in[(size_t)(kb + ty + r*8)*Nn + nb + tx];
  __syncthreads();
#pragma unroll
  for (int r = 0; r < 4; ++r)
    out[(size_t)(nb + ty + r*8)*K + kb + tx] = f2bf(ts[tx][ty + r*8]);
}

// Wcomb^T via small MFMA GEMM (round-4 structure, EPI4 only; 8 blocks, tiny)
__global__ __launch_bounds__(256) void gemm_wcomb(
    const ushort* __restrict__ A, const ushort* __restrict__ Bt,
    int K, int Nn, int Mvalid, ushort* __restrict__ OutB)
{
  __shared__ __align__(16) ushort As[128*32];
  __shared__ __align__(16) ushort Bs[128*32];
  const int tid = threadIdx.x;
  const int row0 = blockIdx.y*128, col0 = blockIdx.x*128;
  const int wave = tid >> 6, lane = tid & 63;
  const int wm = (wave & 1)*64, wn = (wave >> 1)*64;
  const int lm = lane & 15, lq = lane >> 4;

  f32x4 acc[4][4];
#pragma unroll
  for (int i = 0; i < 4; ++i)
#pragma unroll
    for (int j = 0; j < 4; ++j) { acc[i][j][0]=0.f; acc[i][j][1]=0.f; acc[i][j][2]=0.f; acc[i][j][3]=0.f; }

  const int c0 = tid, c1 = tid + 256;
  const int r0a = c0 >> 2, k0a = (c0 & 3) << 3;
  const int r1a = c1 >> 2, k1a = (c1 & 3) << 3;

  for (int k0 = 0; k0 < K; k0 += 32) {
    __syncthreads();
    __builtin_amdgcn_global_load_lds(
        (const __attribute__((address_space(1))) void*)(A + (size_t)(row0 + r0a)*K + k0 + k0a),
        (__attribute__((address_space(3))) void*)(As + c0*8), 16, 0, 0);
    __builtin_amdgcn_global_load_lds(
        (const __attribute__((address_space(1))) void*)(A + (size_t)(row0 + r1a)*K + k0 + k1a),
        (__attribute__((address_space(3))) void*)(As + c1*8), 16, 0, 0);
    __builtin_amdgcn_global_load_lds(
        (const __attribute__((address_space(1))) void*)(Bt + (size_t)(col0 + r0a)*K + k0 + k0a),
        (__attribute__((address_space(3))) void*)(Bs + c0*8), 16, 0, 0);
    __builtin_amdgcn_global_load_lds(
        (const __attribute__((address_space(1))) void*)(Bt + (size_t)(col0 + r1a)*K + k0 + k1a),
        (__attribute__((address_space(3))) void*)(Bs + c1*8), 16, 0, 0);
    __syncthreads();

    bf16x8 af[4], bfr[4];
#pragma unroll
    for (int i = 0; i < 4; ++i)
      af[i] = *(const bf16x8*)&As[(wm + i*16 + lm)*32 + lq*8];
#pragma unroll
    for (int j = 0; j < 4; ++j)
      bfr[j] = *(const bf16x8*)&Bs[(wn + j*16 + lm)*32 + lq*8];
#pragma unroll
    for (int i = 0; i < 4; ++i)
#pragma unroll
      for (int j = 0; j < 4; ++j)
        acc[i][j] = __builtin_amdgcn_mfma_f32_16x16x32_bf16(af[i], bfr[j], acc[i][j], 0, 0, 0);
  }
#pragma unroll
  for (int i = 0; i < 4; ++i)
#pragma unroll
    for (int reg = 0; reg < 4; ++reg) {
      const int r = row0 + wm + i*16 + lq*4 + reg;
#pragma unroll
      for (int j = 0; j < 4; ++j) {
        const int cc = col0 + wn + j*16 + lm;
        OutB[(size_t)cc*Mvalid + r] = f2bf(acc[i][j][reg]);   // transposed store
      }
    }
}

// ---------------------------------------------------------------------------
// MEGA h-branch kernel: per 32-row block computes
//   Hm = h@W_mu (regs) -> z_h (LDS) -> T1half = tanh(z_h@W_r1half) (LDS)
//   -> Hm2 += T1half@Wcomb_half (regs, 2 halves) -> fused loss reduction.
// No intermediates to HBM. 512 threads = 8 waves; wave = 16 rows x 64 cols.
// Staging: B tiles via global_load_lds in 5-chunk rows (pitch PB=40, 2-way only).
// ---------------------------------------------------------------------------
__global__ __launch_bounds__(512, 4) void mega_h(
    const float* __restrict__ h, const float* __restrict__ eps,
    const ushort* __restrict__ wmut, const ushort* __restrict__ wr1t,
    const ushort* __restrict__ wct,
    const int* __restrict__ index, const float* __restrict__ t,
    const float* __restrict__ gph, double* __restrict__ lossh)
{
  __shared__ __align__(16) ushort zhL[MB*PZ];     // 16896 B
  __shared__ __align__(16) ushort T1L[MB*PZ];     // 16896 B (reused as h staging in p0)
  __shared__ __align__(16) ushort Bst[1280*8];    // 20480 B
  __shared__ double smr[8];

  const int tid  = threadIdx.x;
  const int wave = tid >> 6, lane = tid & 63;
  const int lm = lane & 15, lq = lane >> 4;
  const int rowbase = (wave & 1) * 16;
  const int colbase = (wave >> 1) * 64;
  const int row0g = blockIdx.x * MB;

  // per-row t (4 rows per thread: local row = rowbase + lq*4 + reg)
  float tn[4];
#pragma unroll
  for (int reg = 0; reg < 4; ++reg)
    tn[reg] = t[index[row0g + rowbase + lq*4 + reg]];

  // ---- staging helper: 256 outer x 32 k tile, 5 chunks/row (4 data + 1 dup pad)
  auto stageB = [&](const ushort* src, int ldb, int kw) {
    for (int c = tid; c < 1280; c += 512) {
      int outer = c / 5;
      int sub = c - outer*5; sub = (sub == 4) ? 0 : sub;
      __builtin_amdgcn_global_load_lds(
          (const __attribute__((address_space(1))) void*)(src + (size_t)outer*ldb + kw + sub*8),
          (__attribute__((address_space(3))) void*)(Bst + c*8), 16, 0, 0);
    }
  };
  auto mfmaStep = [&](const ushort* Abase, int apitch, int aoff, f32x4 acc[4]) {
    bf16x8 af = *(const bf16x8*)&Abase[(rowbase + lm)*apitch + aoff + lq*8];
#pragma unroll
    for (int j = 0; j < 4; ++j) {
      bf16x8 bfv = *(const bf16x8*)&Bst[(colbase + j*16 + lm)*PB + lq*8];
      acc[j] = __builtin_amdgcn_mfma_f32_16x16x32_bf16(af, bfv, acc[j], 0, 0, 0);
    }
  };

  // ================= phase 0: Hm = h @ W_mu =================
  f32x4 hm[4];
#pragma unroll
  for (int j = 0; j < 4; ++j) { hm[j][0]=0.f; hm[j][1]=0.f; hm[j][2]=0.f; hm[j][3]=0.f; }

  {
    const int arow = tid >> 4, ac2 = (tid & 15) * 2;   // 32 rows x 16 float2
    for (int kw = 0; kw < 256; kw += 32) {
      __syncthreads();
      // stage A: h fp32 -> bf16 into T1L region (pitch PB)
      float2 hv = *(const float2*)&h[(size_t)(row0g + arow)*256 + kw + ac2];
      ushort2 hp; hp.x = f2bf(hv.x); hp.y = f2bf(hv.y);
      *(ushort2*)&T1L[arow*PB + ac2] = hp;
      stageB(wmut, 256, kw);
      __syncthreads();
      mfmaStep(T1L, PB, 0, hm);
    }
  }

  // epilogue p0: z_h = Hm*(1-t) + sig*eps  -> zh LDS (bf16)
#pragma unroll
  for (int reg = 0; reg < 4; ++reg) {
    const int rl = rowbase + lq*4 + reg;
    const float s0 = 1.0f - tn[reg], s1 = 0.1f + 0.9f*tn[reg];
#pragma unroll
    for (int j = 0; j < 4; ++j) {
      const int cl = colbase + j*16 + lm;
      const float e = eps[(size_t)(row0g + rl)*256 + cl];
      zhL[rl*PZ + cl] = f2bf(hm[j][reg]*s0 + s1*e);
    }
  }

  // ============ phases 1&2 interleaved over 256-col halves of T1 ============
  f32x4 hm2[4];
#pragma unroll
  for (int j = 0; j < 4; ++j) { hm2[j][0]=0.f; hm2[j][1]=0.f; hm2[j][2]=0.f; hm2[j][3]=0.f; }

  for (int half = 0; half < 2; ++half) {
    // p1: T1half = tanh(z_h @ W_r1[:, half*256 .. +255])
    f32x4 t1a[4];
#pragma unroll
    for (int j = 0; j < 4; ++j) { t1a[j][0]=0.f; t1a[j][1]=0.f; t1a[j][2]=0.f; t1a[j][3]=0.f; }
    for (int kw = 0; kw < 256; kw += 32) {
      __syncthreads();
      stageB(wr1t + (size_t)half*256*256, 256, kw);
      __syncthreads();
      mfmaStep(zhL, PZ, kw, t1a);
    }
#pragma unroll
    for (int reg = 0; reg < 4; ++reg) {
      const int rl = rowbase + lq*4 + reg;
#pragma unroll
      for (int j = 0; j < 4; ++j)
        T1L[rl*PZ + colbase + j*16 + lm] = f2bf(tanh_fast(t1a[j][reg]));
    }
    // p2: Hm2 += T1half @ Wcomb[half*256 .. , :]   (B = Wcomb^T cols k-half)
    for (int kw = 0; kw < 256; kw += 32) {
      __syncthreads();
      stageB(wct + half*256, 512, kw);
      __syncthreads();
      mfmaStep(T1L, PZ, kw, hm2);
    }
  }

  // ================= fused loss epilogue =================
  const float sp = log1pf(expf(gph[0]));
  float local = 0.0f;
#pragma unroll
  for (int reg = 0; reg < 4; ++reg) {
    const float gh  = 0.1f + sp*tn[reg];
    const float sig = 0.1f + 0.9f*tn[reg];
    const float fac = 1.0f + (0.9f + 0.5f*gh*gh/sig)*(1.0f - tn[reg])/sig;
    const float sc  = fac/gh;
#pragma unroll
    for (int j = 0; j < 4; ++j) {
      const float d = (hm[j][reg] - hm2[j][reg]) * sc;
      local += d*d;
    }
  }
  double v = (double)local;
#pragma unroll
  for (int off = 32; off > 0; off >>= 1) v += __shfl_down(v, off, 64);
  if (lane == 0) smr[wave] = v;
  __syncthreads();
  if (tid == 0) {
    double s = 0.0;
#pragma unroll
    for (int i = 0; i < 8; ++i) s += smr[i];
    atomicAdd(lossh, s);
  }
}

__global__ void finalize_kernel(const double* lossh, const double* lossp,
                                float* out, int N, int DH)
{
  if (threadIdx.x == 0) {
    out[0] = (float)(lossh[0] / ((double)N * (double)DH));
    out[1] = (float)(lossp[0] / ((double)N * 3.0));
  }
}

// ---------------------------------------------------------------------------
extern "C" void kernel_launch(void* const* d_in, const int* in_sizes, int n_in,
                              void* d_out, int out_size, void* d_ws, size_t ws_size,
                              hipStream_t stream) {
  const float* t      = (const float*)d_in[0];
  const float* h      = (const float*)d_in[1];
  const float* pos    = (const float*)d_in[2];
  const float* eps_h  = (const float*)d_in[3];
  const float* eps_p  = (const float*)d_in[4];
  const float* gph    = (const float*)d_in[5];
  const float* gpp    = (const float*)d_in[6];
  const float* W_mu   = (const float*)d_in[7];
  const float* W_r1   = (const float*)d_in[8];
  const float* W_r2   = (const float*)d_in[9];
  const int*   index  = (const int*)d_in[10];
  const int B = in_sizes[0];
  const int N = in_sizes[10];
  const int DH = 256, DH2 = 512;

  char* ws = (char*)d_ws;
  size_t off = 0;
  auto alloc = [&](size_t nbytes) { size_t o = off; off += (nbytes + 255) & ~(size_t)255; return o; };

  size_t o_loss = alloc(16);                             // 2 doubles (zeroed)
  size_t o_wmut = alloc((size_t)DH*DH*2);                // W_mu^T  [256][256]
  size_t o_wr1t = alloc((size_t)DH2*DH*2);               // W_r1^T  [512][256]
  size_t o_wr2b = alloc((size_t)DH2*DH*2);               // W_r2 bf16 [512][256]
  size_t o_wct  = alloc((size_t)DH*DH2*2);               // Wcomb^T [256][512]

  hipMemsetAsync(ws + o_loss, 0, 16, stream);

  double* lossh = (double*)(ws + o_loss);
  double* lossp = lossh + 1;
  ushort* wmut = (ushort*)(ws + o_wmut);
  ushort* wr1t = (ushort*)(ws + o_wr1t);
  ushort* wr2b = (ushort*)(ws + o_wr2b);
  ushort* wct  = (ushort*)(ws + o_wct);

  // ---- pos branch ----
  pos_fused<<<B, 64, 0, stream>>>(N, pos, eps_p, index, t, gpp, lossp);

  // ---- weight prep (tiny) ----
  cvt_bf16<<<128, NTHREADS, 0, stream>>>((const float4*)W_r2, (ushort4*)wr2b, DH2*DH/4);
  transpose_cvt<<<dim3(DH/32,  DH/32), NTHREADS, 0, stream>>>(W_mu, wmut, DH, DH);
  transpose_cvt<<<dim3(DH2/32, DH/32), NTHREADS, 0, stream>>>(W_r1, wr1t, DH, DH2);
  // Wcomb^T = (W_r2 @ W_mu)^T
  gemm_wcomb<<<dim3(DH/128, DH2/128), 256, 0, stream>>>(wr2b, wmut, DH, DH, DH2, wct);

  // ---- fused h branch: one kernel, no HBM intermediates ----
  mega_h<<<N/MB, 512, 0, stream>>>(h, eps_h, wmut, wr1t, wct, index, t, gph, lossh);

  finalize_kernel<<<1, 64, 0, stream>>>(lossh, lossp, (float*)d_out, N, DH);
}